// Round 1
// baseline (1147.350 us; speedup 1.0000x reference)
//
#include <hip/hip_runtime.h>
#include <math.h>

// Problem constants (GPT2 decode attention, fp32)
#define BATCH   32
#define NH      16
#define HD      64      // head dim
#define T_ALL   2048    // cached 2047 + 1 new
#define T_CACHE 2047
#define HID     1024
#define H3      3072
#define QK_SCALE 0.125f // 64^-0.5
#define NCHUNK  8       // token chunks per (b,h) for flash-decoding split
#define CHTOK   256     // tokens per chunk
#define KSPLIT  8       // k-split for the GEMV kernels

// ---------------------------------------------------------------------------
// GEMV: out_part[ks][b][c] = sum_{k in split ks} X[b][k] * W[k][c]
// One thread owns column c for ALL 32 batches -> W is read once from HBM.
// ---------------------------------------------------------------------------
__global__ __launch_bounds__(256) void gemv_part_kernel(
    const float* __restrict__ X, const float* __restrict__ W,
    float* __restrict__ part, int N, int Kdim)
{
    const int c  = blockIdx.x * 256 + threadIdx.x;
    const int ks = blockIdx.y;
    const int kchunk = Kdim / KSPLIT;
    float acc[BATCH];
#pragma unroll
    for (int b = 0; b < BATCH; ++b) acc[b] = 0.f;
    const int k0 = ks * kchunk;
    for (int k = k0; k < k0 + kchunk; ++k) {
        const float w = W[(size_t)k * N + c];
#pragma unroll
        for (int b = 0; b < BATCH; ++b)
            acc[b] = fmaf(X[b * Kdim + k], w, acc[b]);
    }
#pragma unroll
    for (int b = 0; b < BATCH; ++b)
        part[((size_t)ks * BATCH + b) * N + c] = acc[b];
}

__global__ __launch_bounds__(256) void gemv_reduce_kernel(
    const float* __restrict__ part, const float* __restrict__ bias,
    float* __restrict__ out, int N)
{
    const int c = blockIdx.x * 256 + threadIdx.x;
    const int b = blockIdx.y;
    float acc = bias[c];
#pragma unroll
    for (int ks = 0; ks < KSPLIT; ++ks)
        acc += part[((size_t)ks * BATCH + b) * N + c];
    out[(size_t)b * N + c] = acc;
}

// ---------------------------------------------------------------------------
// Fused cache-copy + flash-decoding attention chunk.
// grid = (NCHUNK, NH, BATCH), block = 256 (4 waves).
// Wave layout: lane = tgrp*16 + dgrp. Each iteration a wave handles 4
// consecutive tokens (tgrp) x 16 float4 dim-groups (dgrp) = 1 KiB coalesced.
// K/V rows are read once: copied to the output cache AND fed to the online
// softmax. Chunk partial (m, l, o[64]) goes to workspace.
// ---------------------------------------------------------------------------
__global__ __launch_bounds__(256) void fused_copy_attn_kernel(
    const float* __restrict__ kc, const float* __restrict__ vc,
    const float* __restrict__ qkv, const int* __restrict__ seq_lens,
    float* __restrict__ Kout, float* __restrict__ Vout,
    float* __restrict__ Pm, float* __restrict__ Pl, float* __restrict__ Po)
{
    const int chunk = blockIdx.x;
    const int h     = blockIdx.y;
    const int b     = blockIdx.z;
    const int tid   = threadIdx.x;
    const int wave  = tid >> 6;
    const int lane  = tid & 63;
    const int dgrp  = lane & 15;   // which float4 of the 64-dim row
    const int tgrp  = lane >> 4;   // which of 4 tokens in this iteration

    const int bh   = b * NH + h;
    const int slen = seq_lens[b];

    const float4 q4 = ((const float4*)(qkv + (size_t)b * H3 + h * HD))[dgrp];

    const float4* kc4 = (const float4*)(kc + (size_t)bh * T_CACHE * HD);
    const float4* vc4 = (const float4*)(vc + (size_t)bh * T_CACHE * HD);
    float4* Ko4 = (float4*)(Kout + (size_t)bh * T_ALL * HD);
    float4* Vo4 = (float4*)(Vout + (size_t)bh * T_ALL * HD);

    float m = -1e30f, l = 0.f;
    float4 o = make_float4(0.f, 0.f, 0.f, 0.f);

    const int t0 = chunk * CHTOK + wave * 64;
    for (int i = 0; i < 16; ++i) {
        const int t = t0 + i * 4 + tgrp;
        float4 kv = make_float4(0.f, 0.f, 0.f, 0.f);
        float4 vv = make_float4(0.f, 0.f, 0.f, 0.f);
        const bool incache = (t < T_CACHE);
        if (incache) {
            kv = kc4[t * 16 + dgrp];
            vv = vc4[t * 16 + dgrp];
            Ko4[t * 16 + dgrp] = kv;
            Vo4[t * 16 + dgrp] = vv;
        }
        const bool valid = incache && (t < slen);
        // dot(q, K[t]) across the 16-lane dim group
        float s = kv.x * q4.x + kv.y * q4.y + kv.z * q4.z + kv.w * q4.w;
        s += __shfl_xor(s, 1);
        s += __shfl_xor(s, 2);
        s += __shfl_xor(s, 4);
        s += __shfl_xor(s, 8);
        s = valid ? s * QK_SCALE : -1e30f;
        // wave-wide max over the 4 tokens
        float mx = s;
        mx = fmaxf(mx, __shfl_xor(mx, 16));
        mx = fmaxf(mx, __shfl_xor(mx, 32));
        const float mn    = fmaxf(m, mx);
        const float alpha = __expf(m - mn);          // ==1 when both -1e30
        const float p     = valid ? __expf(s - mn) : 0.f;
        float ps = p;
        ps += __shfl_xor(ps, 16);
        ps += __shfl_xor(ps, 32);
        l = l * alpha + ps;
        m = mn;
        o.x = o.x * alpha + p * vv.x;
        o.y = o.y * alpha + p * vv.y;
        o.z = o.z * alpha + p * vv.z;
        o.w = o.w * alpha + p * vv.w;
    }
    // reduce o over the 4 token groups (all lanes end with their dgrp's total)
    o.x += __shfl_xor(o.x, 16); o.x += __shfl_xor(o.x, 32);
    o.y += __shfl_xor(o.y, 16); o.y += __shfl_xor(o.y, 32);
    o.z += __shfl_xor(o.z, 16); o.z += __shfl_xor(o.z, 32);
    o.w += __shfl_xor(o.w, 16); o.w += __shfl_xor(o.w, 32);

    __shared__ float sm[4], sl[4];
    __shared__ float so[4][HD];
    if (lane == 0) { sm[wave] = m; sl[wave] = l; }
    if (lane < 16) ((float4*)(so[wave]))[lane] = o;
    __syncthreads();

    if (tid < HD) {
        const int d = tid;
        const float m0 = sm[0], m1 = sm[1], m2 = sm[2], m3 = sm[3];
        const float mc = fmaxf(fmaxf(m0, m1), fmaxf(m2, m3));
        const float e0 = __expf(m0 - mc), e1 = __expf(m1 - mc);
        const float e2 = __expf(m2 - mc), e3 = __expf(m3 - mc);
        const float lc = sl[0]*e0 + sl[1]*e1 + sl[2]*e2 + sl[3]*e3;
        const float oc = so[0][d]*e0 + so[1][d]*e1 + so[2][d]*e2 + so[3][d]*e3;
        const int pb = bh * NCHUNK + chunk;
        Po[(size_t)pb * HD + d] = oc;
        if (d == 0) { Pm[pb] = mc; Pl[pb] = lc; }
    }
}

// ---------------------------------------------------------------------------
// Combine chunk partials + the always-visible new token; also append the new
// k/v row to the output caches. grid = 512 (b*NH+h), block = 64 (one wave).
// ---------------------------------------------------------------------------
__global__ __launch_bounds__(64) void combine_kernel(
    const float* __restrict__ qkv,
    const float* __restrict__ Pm, const float* __restrict__ Pl,
    const float* __restrict__ Po,
    float* __restrict__ attn, float* __restrict__ Kout, float* __restrict__ Vout)
{
    const int bh = blockIdx.x;
    const int b = bh >> 4, h = bh & 15;
    const int d = threadIdx.x;     // 0..63

    const float* qb = qkv + (size_t)b * H3;
    const float qd = qb[h * HD + d];
    const float kn = qb[HID  + h * HD + d];
    const float vn = qb[2*HID + h * HD + d];

    // append new token row (position T_ALL-1)
    Kout[((size_t)bh * T_ALL + (T_ALL - 1)) * HD + d] = kn;
    Vout[((size_t)bh * T_ALL + (T_ALL - 1)) * HD + d] = vn;

    // new-token score (always valid)
    float s = qd * kn;
    s += __shfl_xor(s, 1);
    s += __shfl_xor(s, 2);
    s += __shfl_xor(s, 4);
    s += __shfl_xor(s, 8);
    s += __shfl_xor(s, 16);
    s += __shfl_xor(s, 32);
    s *= QK_SCALE;

    float mg = s;
#pragma unroll
    for (int c = 0; c < NCHUNK; ++c)
        mg = fmaxf(mg, Pm[bh * NCHUNK + c]);

    float L   = __expf(s - mg);   // p_new
    float acc = L * vn;
#pragma unroll
    for (int c = 0; c < NCHUNK; ++c) {
        const float e = __expf(Pm[bh * NCHUNK + c] - mg);
        acc += Po[(size_t)(bh * NCHUNK + c) * HD + d] * e;
        L   += Pl[bh * NCHUNK + c] * e;
    }
    attn[(size_t)b * HID + h * HD + d] = acc / L;
}

// ---------------------------------------------------------------------------
extern "C" void kernel_launch(void* const* d_in, const int* in_sizes, int n_in,
                              void* d_out, int out_size, void* d_ws, size_t ws_size,
                              hipStream_t stream)
{
    const float* hs       = (const float*)d_in[0];   // [32,1,1024]
    const float* kc       = (const float*)d_in[1];   // [32,16,2047,64]
    const float* vc       = (const float*)d_in[2];   // [32,16,2047,64]
    // d_in[3] block_tables: unused by the reference math
    const int*   seq_lens = (const int*)d_in[4];     // [32]
    // d_in[5] max_seq_len: == 2048, hardcoded
    const float* W_attn   = (const float*)d_in[6];   // [1024,3072]
    const float* b_attn   = (const float*)d_in[7];   // [3072]
    const float* W_proj   = (const float*)d_in[8];   // [1024,1024]
    const float* b_proj   = (const float*)d_in[9];   // [1024]

    float* out_attn = (float*)d_out;                           // 32*1024
    float* Kout = out_attn + (size_t)BATCH * HID;              // 32*16*2048*64
    float* Vout = Kout + (size_t)BATCH * NH * T_ALL * HD;

    // workspace layout (floats)
    float* w = (float*)d_ws;
    float* w_qkv_part  = w;                       // 8*32*3072  = 786432
    float* w_qkv       = w_qkv_part + (size_t)KSPLIT * BATCH * H3;   // 98304
    float* w_Pm        = w_qkv + (size_t)BATCH * H3;                 // 4096
    float* w_Pl        = w_Pm + BATCH * NH * NCHUNK;                 // 4096
    float* w_Po        = w_Pl + BATCH * NH * NCHUNK;                 // 262144
    float* w_attnvec   = w_Po + (size_t)BATCH * NH * NCHUNK * HD;    // 32768
    float* w_proj_part = w_attnvec + (size_t)BATCH * HID;            // 262144

    // 1) qkv = hs @ W_attn + b_attn
    gemv_part_kernel<<<dim3(H3 / 256, KSPLIT), 256, 0, stream>>>(
        hs, W_attn, w_qkv_part, H3, HID);
    gemv_reduce_kernel<<<dim3(H3 / 256, BATCH), 256, 0, stream>>>(
        w_qkv_part, b_attn, w_qkv, H3);

    // 2) fused cache copy + flash-decoding chunks
    fused_copy_attn_kernel<<<dim3(NCHUNK, NH, BATCH), 256, 0, stream>>>(
        kc, vc, w_qkv, seq_lens, Kout, Vout, w_Pm, w_Pl, w_Po);

    // 3) combine partials + new token, append new k/v rows
    combine_kernel<<<dim3(BATCH * NH), 64, 0, stream>>>(
        w_qkv, w_Pm, w_Pl, w_Po, w_attnvec, Kout, Vout);

    // 4) out = attn @ W_proj + b_proj
    gemv_part_kernel<<<dim3(HID / 256, KSPLIT), 256, 0, stream>>>(
        w_attnvec, W_proj, w_proj_part, HID, HID);
    gemv_reduce_kernel<<<dim3(HID / 256, BATCH), 256, 0, stream>>>(
        w_proj_part, b_proj, out_attn, HID);
}